// Round 5
// baseline (564.364 us; speedup 1.0000x reference)
//
#include <hip/hip_runtime.h>
#include <cstdint>

#define N_NODES 50000
#define N_EDGES 1600000
#define NH 4
#define CC 32
#define HC 128          // NH*CC
#define LAT 32
#define NEG_SLOPE 0.2f

// ---------------- bf16 helpers (RNE pack, shift-unpack) ----------------
__device__ __forceinline__ float bflo(uint32_t u) {
    union { uint32_t i; float f; } c; c.i = u << 16; return c.f;
}
__device__ __forceinline__ float bfhi(uint32_t u) {
    union { uint32_t i; float f; } c; c.i = u & 0xFFFF0000u; return c.f;
}
__device__ __forceinline__ uint32_t f2bf(float f) {
    union { float f; uint32_t i; } c; c.f = f;
    return (c.i + 0x7FFFu + ((c.i >> 16) & 1u)) >> 16;
}
__device__ __forceinline__ uint32_t pack2(float a, float b) {
    return f2bf(a) | (f2bf(b) << 16);
}

// ---------------------------------------------------------------- kernels

// small precompute:
//   v[d*4+h]     = sum_c W_edge[d,h*32+c] * att_edge[h,c]        (d<7)
//   u_src[i*4+h] = sum_c W_gat [i,h*32+c] * att_src[h,c]         (i<3)
//   u_dst[i*4+h] = sum_c W_gat [i,h*32+c] * att_dst[h,c]
__global__ void k_v(const float* __restrict__ W_edge,
                    const float* __restrict__ att_edge,
                    const float* __restrict__ W_gat,
                    const float* __restrict__ att_src,
                    const float* __restrict__ att_dst,
                    float* __restrict__ v,
                    float* __restrict__ u_src,
                    float* __restrict__ u_dst) {
    int t = threadIdx.x;
    if (t < 28) {
        int d = t >> 2, h = t & 3;
        float s = 0.f;
        #pragma unroll
        for (int c = 0; c < 32; ++c)
            s += W_edge[d * 128 + h * 32 + c] * att_edge[h * 32 + c];
        v[t] = s;
    } else if (t < 40) {
        int q = t - 28; int i = q >> 2, h = q & 3;
        float s = 0.f;
        #pragma unroll
        for (int c = 0; c < 32; ++c)
            s += W_gat[i * 128 + h * 32 + c] * att_src[h * 32 + c];
        u_src[q] = s;
    } else if (t < 52) {
        int q = t - 40; int i = q >> 2, h = q & 3;
        float s = 0.f;
        #pragma unroll
        for (int c = 0; c < 32; ++c)
            s += W_gat[i * 128 + h * 32 + c] * att_dst[h * 32 + c];
        u_dst[q] = s;
    }
}

// xp2[n*64+l] = bf16x2 of (xp[n,2l], xp[n,2l+1]); fp32 xp never materialized
__global__ __launch_bounds__(256) void k_xp(const float* __restrict__ x,
                                            const float* __restrict__ W_gat,
                                            uint32_t* __restrict__ xp2) {
    int k = blockIdx.x * 256 + threadIdx.x;
    if (k >= N_NODES * 64) return;
    int n = k >> 6, c = (k & 63) * 2;
    float x0 = x[n * 3 + 0], x1 = x[n * 3 + 1], x2 = x[n * 3 + 2];
    float a = x0 * W_gat[c]     + x1 * W_gat[128 + c]     + x2 * W_gat[256 + c];
    float b = x0 * W_gat[c + 1] + x1 * W_gat[128 + c + 1] + x2 * W_gat[256 + c + 1];
    xp2[k] = pack2(a, b);
}

// per edge: count in-degree (int atomics only)
__global__ __launch_bounds__(256) void k_cnt(const int* __restrict__ ei,
                                             int* __restrict__ cnt) {
    int e = blockIdx.x * 256 + threadIdx.x;
    if (e >= N_EDGES) return;
    atomicAdd(&cnt[ei[N_EDGES + e]], 1);
}

// single-block exclusive prefix sum over cnt -> rowptr[N+1]
__global__ __launch_bounds__(1024) void k_scan(const int* __restrict__ cnt,
                                               int* __restrict__ rowptr) {
    __shared__ int part[1024];
    int t = threadIdx.x;
    const int W = (N_NODES + 1023) / 1024;
    int lo = t * W, hi = min(lo + W, N_NODES);
    int s = 0;
    for (int i = lo; i < hi; ++i) s += cnt[i];
    part[t] = s;
    __syncthreads();
    for (int off = 1; off < 1024; off <<= 1) {
        int vv = (t >= off) ? part[t - off] : 0;
        __syncthreads();
        part[t] += vv;
        __syncthreads();
    }
    int run = part[t] - s;   // exclusive base
    for (int i = lo; i < hi; ++i) { rowptr[i] = run; run += cnt[i]; }
    if (t == 1023) rowptr[N_NODES] = part[1023];
}

// per node: a_src[n,h] = x[n,:].u_src[:,h]; a_dst likewise (3-dots, exact fp32)
__global__ __launch_bounds__(256) void k_node(const float* __restrict__ x,
                                              const float* __restrict__ u_src,
                                              const float* __restrict__ u_dst,
                                              float4* __restrict__ a_src,
                                              float4* __restrict__ a_dst) {
    int n = blockIdx.x * 256 + threadIdx.x;
    if (n >= N_NODES) return;
    float x0 = x[n * 3 + 0], x1 = x[n * 3 + 1], x2 = x[n * 3 + 2];
    float s[4], d[4];
    #pragma unroll
    for (int h = 0; h < 4; ++h) {
        s[h] = x0 * u_src[h] + x1 * u_src[4 + h] + x2 * u_src[8 + h];
        d[h] = x0 * u_dst[h] + x1 * u_dst[4 + h] + x2 * u_dst[8 + h];
    }
    a_src[n] = make_float4(s[0], s[1], s[2], s[3]);
    a_dst[n] = make_float4(d[0], d[1], d[2], d[3]);
}

// per edge: aeh = edge_attr.v (bf16-packed) + src -> ONE aligned 16B record
// into its CSR slot. Single line-touch per edge (was 3 scattered arrays ->
// 197MB WRITE_SIZE; payload is only 32MB). exp/weights moved to k_gather.
__global__ __launch_bounds__(256) void k_scatter(const int* __restrict__ ei,
                                                 const float* __restrict__ edge_attr,
                                                 const float* __restrict__ v,
                                                 const int* __restrict__ rowptr,
                                                 int* __restrict__ cnt2,
                                                 uint4* __restrict__ csr) {
    __shared__ float vs[28];
    __shared__ float ea_s[256 * 7];
    int t = threadIdx.x;
    if (t < 28) vs[t] = v[t];
    int e0 = blockIdx.x * 256;
    #pragma unroll
    for (int i = 0; i < 7; ++i)
        ea_s[t + i * 256] = edge_attr[e0 * 7 + t + i * 256];   // coalesced
    __syncthreads();
    int e = e0 + t;
    int src = ei[e];
    int dst = ei[N_EDGES + e];
    float ea[7];
    #pragma unroll
    for (int d = 0; d < 7; ++d) ea[d] = ea_s[t * 7 + d];
    float aeo[4];
    #pragma unroll
    for (int h = 0; h < 4; ++h) {
        float aeh = 0.f;
        #pragma unroll
        for (int d = 0; d < 7; ++d) aeh += ea[d] * vs[d * 4 + h];
        aeo[h] = aeh;
    }
    int pos = rowptr[dst] + atomicAdd(&cnt2[dst], 1);
    csr[pos] = make_uint4(pack2(aeo[0], aeo[1]), pack2(aeo[2], aeo[3]),
                          (uint32_t)src, 0u);
}

// 2 nodes per 128-thr block (one wave each), 2 channels/lane.
// Single pass per edge: al = ae + a_src[src,h] + a_dst[n,h]; w = exp(lrelu(al));
// accumulate {acc, den, aesum}; self-loop term added at the end (additive).
__global__ __launch_bounds__(128) void k_gather(const int* __restrict__ rowptr,
                                                const uint4* __restrict__ csr,
                                                const uint32_t* __restrict__ xp2,
                                                const float* __restrict__ a_src,
                                                const float* __restrict__ a_dst,
                                                const float* __restrict__ bias_gat,
                                                float2* __restrict__ h_buf) {
    int n = blockIdx.x * 2 + (threadIdx.x >> 6);
    int l = threadIdx.x & 63;     // lane 0..63; channels 2l, 2l+1
    int h = l >> 4;               // head
    int start = rowptr[n], end = rowptr[n + 1];
    int deg = end - start;

    float ad_n = a_dst[n * 4 + h];
    float as_n = a_src[n * 4 + h];

    float acc0 = 0.f, acc1 = 0.f, den = 0.f, aesum = 0.f;
    for (int p = start; p < end; ++p) {
        uint4 rec = csr[p];                    // wave-uniform -> scalar loads
        uint32_t aw = (h < 2) ? rec.x : rec.y;
        float ae = (h & 1) ? bfhi(aw) : bflo(aw);
        int src = (int)rec.z;
        float al = ae + a_src[src * 4 + h] + ad_n;
        al = al > 0.f ? al : NEG_SLOPE * al;
        float w = __expf(al);
        uint32_t xu = xp2[src * 64 + l];
        acc0 += w * bflo(xu);
        acc1 += w * bfhi(xu);
        den  += w;
        aesum += ae;
    }
    // self loop: edge_attr = mean of incoming aeh (linearity of the .v dot)
    float invd = (deg > 0) ? (1.0f / (float)deg) : 1.0f;
    float al0 = as_n + ad_n + aesum * invd;
    al0 = al0 > 0.f ? al0 : NEG_SLOPE * al0;
    float w0 = __expf(al0);
    uint32_t xs = xp2[n * 64 + l];
    acc0 += w0 * bflo(xs);
    acc1 += w0 * bfhi(xs);
    den  += w0;

    float2 bia = ((const float2*)bias_gat)[l];
    float r = 1.0f / den;
    float o0 = acc0 * r + bia.x;
    float o1 = acc1 * r + bia.y;
    o0 = o0 > 0.f ? o0 : (__expf(o0) - 1.0f);   // ELU
    o1 = o1 > 0.f ? o1 : (__expf(o1) - 1.0f);
    h_buf[n * 64 + l] = make_float2(o0, o1);
}

// fused MLP: out = PReLU(h @ W1 + b1) @ W2 + b2 ; 8 rows per 256-thread block
__global__ __launch_bounds__(256) void k_mlp(const float* __restrict__ h_buf,
                                             const float* __restrict__ W1,
                                             const float* __restrict__ b1,
                                             const float* __restrict__ prelu_a,
                                             const float* __restrict__ W2,
                                             const float* __restrict__ b2,
                                             float* __restrict__ out) {
    __shared__ float sh[8][128];
    __shared__ float sh1[8][128];
    int t = threadIdx.x;
    int nb = blockIdx.x * 8;
    #pragma unroll
    for (int i = 0; i < 4; ++i) {
        int idx = t + i * 256;
        sh[idx >> 7][idx & 127] = h_buf[nb * 128 + idx];
    }
    __syncthreads();
    int k = t & 127, g = t >> 7;          // g in {0,1}: rows g*4..g*4+3
    float acc[4];
    float bb = b1[k];
    #pragma unroll
    for (int r = 0; r < 4; ++r) acc[r] = bb;
    for (int d = 0; d < 128; ++d) {
        float wv = W1[d * 128 + k];
        #pragma unroll
        for (int r = 0; r < 4; ++r)
            acc[r] += sh[g * 4 + r][d] * wv;
    }
    float a = prelu_a[0];
    #pragma unroll
    for (int r = 0; r < 4; ++r) {
        float vv = acc[r];
        sh1[g * 4 + r][k] = vv > 0.f ? vv : a * vv;
    }
    __syncthreads();
    int j = t & 31, r2 = t >> 5;
    float o = b2[j];
    for (int d = 0; d < 128; ++d)
        o += sh1[r2][d] * W2[d * 32 + j];
    out[(nb + r2) * 32 + j] = o;
}

// ---------------------------------------------------------------- launch

extern "C" void kernel_launch(void* const* d_in, const int* in_sizes, int n_in,
                              void* d_out, int out_size, void* d_ws, size_t ws_size,
                              hipStream_t stream) {
    const float* x        = (const float*)d_in[0];
    const int*   ei       = (const int*)d_in[1];     // int32 per harness contract
    const float* edge_attr= (const float*)d_in[2];
    const float* W_gat    = (const float*)d_in[3];
    const float* att_src  = (const float*)d_in[4];
    const float* att_dst  = (const float*)d_in[5];
    const float* W_edge   = (const float*)d_in[6];
    const float* att_edge = (const float*)d_in[7];
    const float* bias_gat = (const float*)d_in[8];
    const float* W1       = (const float*)d_in[9];
    const float* b1       = (const float*)d_in[10];
    const float* prelu_a  = (const float*)d_in[11];
    const float* W2       = (const float*)d_in[12];
    const float* b2       = (const float*)d_in[13];
    float*       out      = (float*)d_out;

    char* base = (char*)d_ws;
    size_t off = 0;
    auto alloc = [&](size_t bytes) -> void* {
        void* p = base + off;
        off = (off + bytes + 255) & ~(size_t)255;
        return p;
    };
    int*      cnt     = (int*)     alloc((size_t)N_NODES * 4);   // contiguous with
    int*      cnt2    = (int*)     alloc((size_t)N_NODES * 4);   // cnt: one memset
    int*      rowptr  = (int*)     alloc((size_t)(N_NODES + 1) * 4);
    float*    v       = (float*)   alloc(32 * 4);
    float*    u_src   = (float*)   alloc(16 * 4);
    float*    u_dst   = (float*)   alloc(16 * 4);
    float*    a_src   = (float*)   alloc((size_t)N_NODES * 4 * 4);
    float*    a_dst   = (float*)   alloc((size_t)N_NODES * 4 * 4);
    uint32_t* xp2     = (uint32_t*)alloc((size_t)N_NODES * 64 * 4);
    uint4*    csr     = (uint4*)   alloc((size_t)N_EDGES * 16);
    float*    h_buf   = (float*)   alloc((size_t)N_NODES * 128 * 4);

    // cnt and cnt2 are adjacent in the carve-up: zero both in one memset
    hipMemsetAsync(cnt, 0, (size_t)((char*)rowptr - (char*)cnt), stream);

    k_v   <<<1, 64, 0, stream>>>(W_edge, att_edge, W_gat, att_src, att_dst,
                                 v, u_src, u_dst);
    k_xp  <<<(N_NODES * 64 + 255) / 256, 256, 0, stream>>>(x, W_gat, xp2);
    k_cnt <<<(N_EDGES + 255) / 256, 256, 0, stream>>>(ei, cnt);
    k_scan<<<1, 1024, 0, stream>>>(cnt, rowptr);
    k_node<<<(N_NODES + 255) / 256, 256, 0, stream>>>(
        x, u_src, u_dst, (float4*)a_src, (float4*)a_dst);
    k_scatter<<<N_EDGES / 256, 256, 0, stream>>>(
        ei, edge_attr, v, rowptr, cnt2, csr);
    k_gather<<<N_NODES / 2, 128, 0, stream>>>(
        rowptr, csr, xp2, a_src, a_dst, bias_gat, (float2*)h_buf);
    k_mlp <<<N_NODES / 8, 256, 0, stream>>>(h_buf, W1, b1, prelu_a, W2, b2, out);
}

// Round 6
// 473.536 us; speedup vs baseline: 1.1918x; 1.1918x over previous
//
#include <hip/hip_runtime.h>
#include <cstdint>

#define N_NODES 50000
#define N_EDGES 1600000
#define NH 4
#define CC 32
#define HC 128          // NH*CC
#define LAT 32
#define NEG_SLOPE 0.2f

// k_pre role split (cnt first: atomics are the long pole)
#define NB_CNT  6250                    // N_EDGES/256
#define NB_XP   12500                   // N_NODES*64/256
#define NB_NODE 196                     // ceil(N_NODES/256)
#define NB_PRE  (NB_CNT + NB_XP + NB_NODE + 1)

// ---------------- bf16 helpers (RNE pack, shift-unpack) ----------------
__device__ __forceinline__ float bflo(uint32_t u) {
    union { uint32_t i; float f; } c; c.i = u << 16; return c.f;
}
__device__ __forceinline__ float bfhi(uint32_t u) {
    union { uint32_t i; float f; } c; c.i = u & 0xFFFF0000u; return c.f;
}
__device__ __forceinline__ uint32_t f2bf(float f) {
    union { float f; uint32_t i; } c; c.f = f;
    return (c.i + 0x7FFFu + ((c.i >> 16) & 1u)) >> 16;
}
__device__ __forceinline__ uint32_t pack2(float a, float b) {
    return f2bf(a) | (f2bf(b) << 16);
}

// ---------------------------------------------------------------- kernels

// fused front end: [cnt | xp | node | v] by blockIdx range
__global__ __launch_bounds__(256) void k_pre(const float* __restrict__ x,
                                             const int* __restrict__ ei,
                                             const float* __restrict__ W_gat,
                                             const float* __restrict__ att_src,
                                             const float* __restrict__ att_dst,
                                             const float* __restrict__ W_edge,
                                             const float* __restrict__ att_edge,
                                             int* __restrict__ cnt,
                                             uint32_t* __restrict__ xp2,
                                             float4* __restrict__ a_src,
                                             float4* __restrict__ a_dst,
                                             float* __restrict__ v) {
    int bid = blockIdx.x, t = threadIdx.x;
    if (bid < NB_CNT) {
        // in-degree count (int atomics, L2-resident 200KB)
        int e = bid * 256 + t;
        atomicAdd(&cnt[ei[N_EDGES + e]], 1);
    } else if (bid < NB_CNT + NB_XP) {
        // xp2[n*64+l] = bf16x2 of projected features
        int k = (bid - NB_CNT) * 256 + t;
        int n = k >> 6, c = (k & 63) * 2;
        float x0 = x[n * 3 + 0], x1 = x[n * 3 + 1], x2 = x[n * 3 + 2];
        float a = x0 * W_gat[c]   + x1 * W_gat[128 + c]   + x2 * W_gat[256 + c];
        float b = x0 * W_gat[c+1] + x1 * W_gat[128 + c+1] + x2 * W_gat[256 + c+1];
        xp2[k] = pack2(a, b);
    } else if (bid < NB_CNT + NB_XP + NB_NODE) {
        // a_src[n,h] = x[n,:].u_src[:,h]; u computed in-block (trivial)
        __shared__ float us[12], ud[12];
        if (t < 12) {
            int i = t >> 2, h = t & 3;
            float s = 0.f;
            #pragma unroll
            for (int c = 0; c < 32; ++c)
                s += W_gat[i * 128 + h * 32 + c] * att_src[h * 32 + c];
            us[t] = s;
        } else if (t < 24) {
            int q = t - 12; int i = q >> 2, h = q & 3;
            float s = 0.f;
            #pragma unroll
            for (int c = 0; c < 32; ++c)
                s += W_gat[i * 128 + h * 32 + c] * att_dst[h * 32 + c];
            ud[q] = s;
        }
        __syncthreads();
        int n = (bid - NB_CNT - NB_XP) * 256 + t;
        if (n < N_NODES) {
            float x0 = x[n * 3 + 0], x1 = x[n * 3 + 1], x2 = x[n * 3 + 2];
            float s[4], d[4];
            #pragma unroll
            for (int h = 0; h < 4; ++h) {
                s[h] = x0 * us[h] + x1 * us[4 + h] + x2 * us[8 + h];
                d[h] = x0 * ud[h] + x1 * ud[4 + h] + x2 * ud[8 + h];
            }
            a_src[n] = make_float4(s[0], s[1], s[2], s[3]);
            a_dst[n] = make_float4(d[0], d[1], d[2], d[3]);
        }
    } else {
        // v[d*4+h] = W_edge[d,:] . att_edge (for k_scatter)
        if (t < 28) {
            int d = t >> 2, h = t & 3;
            float s = 0.f;
            #pragma unroll
            for (int c = 0; c < 32; ++c)
                s += W_edge[d * 128 + h * 32 + c] * att_edge[h * 32 + c];
            v[t] = s;
        }
    }
}

// single-block exclusive prefix sum over cnt -> rowptr[N+1]
__global__ __launch_bounds__(1024) void k_scan(const int* __restrict__ cnt,
                                               int* __restrict__ rowptr) {
    __shared__ int part[1024];
    int t = threadIdx.x;
    const int W = (N_NODES + 1023) / 1024;
    int lo = t * W, hi = min(lo + W, N_NODES);
    int s = 0;
    for (int i = lo; i < hi; ++i) s += cnt[i];
    part[t] = s;
    __syncthreads();
    for (int off = 1; off < 1024; off <<= 1) {
        int vv = (t >= off) ? part[t - off] : 0;
        __syncthreads();
        part[t] += vv;
        __syncthreads();
    }
    int run = part[t] - s;   // exclusive base
    for (int i = lo; i < hi; ++i) { rowptr[i] = run; run += cnt[i]; }
    if (t == 1023) rowptr[N_NODES] = part[1023];
}

// per edge: aeh = edge_attr.v (bf16-packed) + src -> ONE aligned 16B record
// into its CSR slot. Slot claimed by DECREMENTING cnt (cnt dead after scan).
__global__ __launch_bounds__(256) void k_scatter(const int* __restrict__ ei,
                                                 const float* __restrict__ edge_attr,
                                                 const float* __restrict__ v,
                                                 const int* __restrict__ rowptr,
                                                 int* __restrict__ cnt,
                                                 uint4* __restrict__ csr) {
    __shared__ float vs[28];
    __shared__ float ea_s[256 * 7];
    int t = threadIdx.x;
    if (t < 28) vs[t] = v[t];
    int e0 = blockIdx.x * 256;
    #pragma unroll
    for (int i = 0; i < 7; ++i)
        ea_s[t + i * 256] = edge_attr[e0 * 7 + t + i * 256];   // coalesced
    __syncthreads();
    int e = e0 + t;
    int src = ei[e];
    int dst = ei[N_EDGES + e];
    float ea[7];
    #pragma unroll
    for (int d = 0; d < 7; ++d) ea[d] = ea_s[t * 7 + d];
    float aeo[4];
    #pragma unroll
    for (int h = 0; h < 4; ++h) {
        float aeh = 0.f;
        #pragma unroll
        for (int d = 0; d < 7; ++d) aeh += ea[d] * vs[d * 4 + h];
        aeo[h] = aeh;
    }
    int c = atomicSub(&cnt[dst], 1);          // c in [1, deg]
    int pos = rowptr[dst] + c - 1;
    csr[pos] = make_uint4(pack2(aeo[0], aeo[1]), pack2(aeo[2], aeo[3]),
                          (uint32_t)src, 0u);
}

// 2 nodes per 128-thr block (one wave each), 2 channels/lane.
// Batch-4 software pipeline: 4 recs -> 4 xp2 + 4 a_src loads in flight,
// breaking the rec->xp dependent-latency chain that bound R5 (166us).
__global__ __launch_bounds__(128) void k_gather(const int* __restrict__ rowptr,
                                                const uint4* __restrict__ csr,
                                                const uint32_t* __restrict__ xp2,
                                                const float* __restrict__ a_src,
                                                const float* __restrict__ a_dst,
                                                const float* __restrict__ bias_gat,
                                                float2* __restrict__ h_buf) {
    int n = blockIdx.x * 2 + (threadIdx.x >> 6);
    int l = threadIdx.x & 63;     // lane 0..63; channels 2l, 2l+1
    int h = l >> 4;               // head
    int start = rowptr[n], end = rowptr[n + 1];
    int deg = end - start;

    float ad_n = a_dst[n * 4 + h];
    float as_n = a_src[n * 4 + h];

    float acc0 = 0.f, acc1 = 0.f, den = 0.f, aesum = 0.f;
    int p = start;
    int pend4 = end - (deg & 3);

    for (; p < pend4; p += 4) {
        uint4 r0 = csr[p + 0];
        uint4 r1 = csr[p + 1];
        uint4 r2 = csr[p + 2];
        uint4 r3 = csr[p + 3];
        int s0 = (int)r0.z, s1 = (int)r1.z, s2 = (int)r2.z, s3 = (int)r3.z;
        uint32_t x0 = xp2[s0 * 64 + l];
        uint32_t x1 = xp2[s1 * 64 + l];
        uint32_t x2 = xp2[s2 * 64 + l];
        uint32_t x3 = xp2[s3 * 64 + l];
        float A0 = a_src[s0 * 4 + h];
        float A1 = a_src[s1 * 4 + h];
        float A2 = a_src[s2 * 4 + h];
        float A3 = a_src[s3 * 4 + h];
        uint32_t aw0 = (h < 2) ? r0.x : r0.y;
        uint32_t aw1 = (h < 2) ? r1.x : r1.y;
        uint32_t aw2 = (h < 2) ? r2.x : r2.y;
        uint32_t aw3 = (h < 2) ? r3.x : r3.y;
        float ae0 = (h & 1) ? bfhi(aw0) : bflo(aw0);
        float ae1 = (h & 1) ? bfhi(aw1) : bflo(aw1);
        float ae2 = (h & 1) ? bfhi(aw2) : bflo(aw2);
        float ae3 = (h & 1) ? bfhi(aw3) : bflo(aw3);
        float al0 = ae0 + A0 + ad_n; al0 = al0 > 0.f ? al0 : NEG_SLOPE * al0;
        float al1 = ae1 + A1 + ad_n; al1 = al1 > 0.f ? al1 : NEG_SLOPE * al1;
        float al2 = ae2 + A2 + ad_n; al2 = al2 > 0.f ? al2 : NEG_SLOPE * al2;
        float al3 = ae3 + A3 + ad_n; al3 = al3 > 0.f ? al3 : NEG_SLOPE * al3;
        float w0 = __expf(al0), w1 = __expf(al1);
        float w2 = __expf(al2), w3 = __expf(al3);
        acc0 += w0 * bflo(x0) + w1 * bflo(x1) + w2 * bflo(x2) + w3 * bflo(x3);
        acc1 += w0 * bfhi(x0) + w1 * bfhi(x1) + w2 * bfhi(x2) + w3 * bfhi(x3);
        den  += (w0 + w1) + (w2 + w3);
        aesum += (ae0 + ae1) + (ae2 + ae3);
    }
    for (; p < end; ++p) {
        uint4 rec = csr[p];
        uint32_t aw = (h < 2) ? rec.x : rec.y;
        float ae = (h & 1) ? bfhi(aw) : bflo(aw);
        int src = (int)rec.z;
        float al = ae + a_src[src * 4 + h] + ad_n;
        al = al > 0.f ? al : NEG_SLOPE * al;
        float w = __expf(al);
        uint32_t xu = xp2[src * 64 + l];
        acc0 += w * bflo(xu);
        acc1 += w * bfhi(xu);
        den  += w;
        aesum += ae;
    }

    // self loop: edge_attr = mean of incoming aeh (linearity of the .v dot)
    float invd = (deg > 0) ? (1.0f / (float)deg) : 1.0f;
    float alS = as_n + ad_n + aesum * invd;
    alS = alS > 0.f ? alS : NEG_SLOPE * alS;
    float wS = __expf(alS);
    uint32_t xs = xp2[n * 64 + l];
    acc0 += wS * bflo(xs);
    acc1 += wS * bfhi(xs);
    den  += wS;

    float2 bia = ((const float2*)bias_gat)[l];
    float r = 1.0f / den;
    float o0 = acc0 * r + bia.x;
    float o1 = acc1 * r + bia.y;
    o0 = o0 > 0.f ? o0 : (__expf(o0) - 1.0f);   // ELU
    o1 = o1 > 0.f ? o1 : (__expf(o1) - 1.0f);
    h_buf[n * 64 + l] = make_float2(o0, o1);
}

// fused MLP: out = PReLU(h @ W1 + b1) @ W2 + b2 ; 8 rows per 256-thread block
__global__ __launch_bounds__(256) void k_mlp(const float* __restrict__ h_buf,
                                             const float* __restrict__ W1,
                                             const float* __restrict__ b1,
                                             const float* __restrict__ prelu_a,
                                             const float* __restrict__ W2,
                                             const float* __restrict__ b2,
                                             float* __restrict__ out) {
    __shared__ float sh[8][128];
    __shared__ float sh1[8][128];
    int t = threadIdx.x;
    int nb = blockIdx.x * 8;
    #pragma unroll
    for (int i = 0; i < 4; ++i) {
        int idx = t + i * 256;
        sh[idx >> 7][idx & 127] = h_buf[nb * 128 + idx];
    }
    __syncthreads();
    int k = t & 127, g = t >> 7;          // g in {0,1}: rows g*4..g*4+3
    float acc[4];
    float bb = b1[k];
    #pragma unroll
    for (int r = 0; r < 4; ++r) acc[r] = bb;
    for (int d = 0; d < 128; ++d) {
        float wv = W1[d * 128 + k];
        #pragma unroll
        for (int r = 0; r < 4; ++r)
            acc[r] += sh[g * 4 + r][d] * wv;
    }
    float a = prelu_a[0];
    #pragma unroll
    for (int r = 0; r < 4; ++r) {
        float vv = acc[r];
        sh1[g * 4 + r][k] = vv > 0.f ? vv : a * vv;
    }
    __syncthreads();
    int j = t & 31, r2 = t >> 5;
    float o = b2[j];
    for (int d = 0; d < 128; ++d)
        o += sh1[r2][d] * W2[d * 32 + j];
    out[(nb + r2) * 32 + j] = o;
}

// ---------------------------------------------------------------- launch

extern "C" void kernel_launch(void* const* d_in, const int* in_sizes, int n_in,
                              void* d_out, int out_size, void* d_ws, size_t ws_size,
                              hipStream_t stream) {
    const float* x        = (const float*)d_in[0];
    const int*   ei       = (const int*)d_in[1];     // int32 per harness contract
    const float* edge_attr= (const float*)d_in[2];
    const float* W_gat    = (const float*)d_in[3];
    const float* att_src  = (const float*)d_in[4];
    const float* att_dst  = (const float*)d_in[5];
    const float* W_edge   = (const float*)d_in[6];
    const float* att_edge = (const float*)d_in[7];
    const float* bias_gat = (const float*)d_in[8];
    const float* W1       = (const float*)d_in[9];
    const float* b1       = (const float*)d_in[10];
    const float* prelu_a  = (const float*)d_in[11];
    const float* W2       = (const float*)d_in[12];
    const float* b2       = (const float*)d_in[13];
    float*       out      = (float*)d_out;

    char* base = (char*)d_ws;
    size_t off = 0;
    auto alloc = [&](size_t bytes) -> void* {
        void* p = base + off;
        off = (off + bytes + 255) & ~(size_t)255;
        return p;
    };
    int*      cnt     = (int*)     alloc((size_t)N_NODES * 4);
    int*      rowptr  = (int*)     alloc((size_t)(N_NODES + 1) * 4);
    float*    v       = (float*)   alloc(32 * 4);
    float*    a_src   = (float*)   alloc((size_t)N_NODES * 4 * 4);
    float*    a_dst   = (float*)   alloc((size_t)N_NODES * 4 * 4);
    uint32_t* xp2     = (uint32_t*)alloc((size_t)N_NODES * 64 * 4);
    uint4*    csr     = (uint4*)   alloc((size_t)N_EDGES * 16);
    float*    h_buf   = (float*)   alloc((size_t)N_NODES * 128 * 4);

    hipMemsetAsync(cnt, 0, (size_t)N_NODES * 4, stream);

    k_pre <<<NB_PRE, 256, 0, stream>>>(x, ei, W_gat, att_src, att_dst,
                                       W_edge, att_edge, cnt, xp2,
                                       (float4*)a_src, (float4*)a_dst, v);
    k_scan<<<1, 1024, 0, stream>>>(cnt, rowptr);
    k_scatter<<<N_EDGES / 256, 256, 0, stream>>>(
        ei, edge_attr, v, rowptr, cnt, csr);
    k_gather<<<N_NODES / 2, 128, 0, stream>>>(
        rowptr, csr, xp2, a_src, a_dst, bias_gat, (float2*)h_buf);
    k_mlp <<<N_NODES / 8, 256, 0, stream>>>(h_buf, W1, b1, prelu_a, W2, b2, out);
}